// Round 12
// baseline (338.804 us; speedup 1.0000x reference)
//
#include <hip/hip_runtime.h>
#include <hip/hip_bf16.h>

// DCell forward, bf16-MFMA. Round-20:
//  * s4s3_fused de-serialized (was top dispatch at 60.4us: MfmaUtil 1.4%,
//    VALU 14.5%, HBM 5%, occ 24.6% -- latency-bound). Three fixes:
//    (1) sp4 fold parallelized: 320 units (2 stats x 160 cols) over all 256
//        threads, 4-way unrolled independent partials -> foldS LDS (was 160
//        threads x 64 serial dependent scalar loads);
//    (2) bn_ss computed inline per lane from foldS (scP table + its ordering
//        constraint removed; ~10 redundant VALU per col);
//    (3) s4 head -> headL LDS -> coalesced 8-float row segments after the
//        existing barrier (was 512 scattered 4B stores from 4/64 lanes).
//    gs (HBM) staging issued before the L2-hot fold so latencies overlap.
//    Fold reassociation: ~1e-7 relative on stats (tolerance 0.015).
//  * Everything else = round-19 (334.8us): reduce0_vec, cvt_w64, stats-in-
//    pack, s2 fusion, atomic stats, gemm_split round-8 body FROZEN
//    (r9/r10/r11/r16 all regressed).
// Stage cfg (T,I,O,C,Gs): s4(256,16,20,0,16) s3(64,144,20,80,64)
//  s2(16,336,77,80,256) s1(4,1332,308,308,1024) s0(1,5328,1229,1232,4096)

#define BDIM 2048
#define OUTW 341

typedef __attribute__((ext_vector_type(8))) short short8;
typedef __attribute__((ext_vector_type(4))) float float4v;
typedef float float4u __attribute__((ext_vector_type(4), aligned(4)));   // 4B-aligned load

static __device__ __forceinline__ unsigned short f2bf(float f) {
    union { float f; unsigned u; } c{f};
    unsigned r = c.u + 0x7FFF + ((c.u >> 16) & 1);  // RNE
    return (unsigned short)(r >> 16);
}
static __device__ __forceinline__ float bf2f(unsigned short s) {
    union { unsigned u; float f; } c{(unsigned)s << 16};
    return c.f;
}

static __device__ __forceinline__ float fast_tanh(float x) {
    float ax = __builtin_fabsf(x);
    float e  = __builtin_amdgcn_exp2f(ax * 2.8853900817779268f);  // e^{2|x|}
    float r  = 1.f - 2.f * __builtin_amdgcn_rcpf(e + 1.f);
    return __builtin_copysignf(r, x);
}

// scale/shift from accumulated (sum, sumsq): identical expression everywhere.
static __device__ __forceinline__ void bn_ss(float sm, float sq, float g, float bb,
                                             float& scale, float& shift) {
    float mu = sm * (1.f / BDIM);
    float var = sq * (1.f / BDIM) - mu * mu;  // biased, matches jnp.var
    scale = rsqrtf(var + 1e-5f) * g;
    shift = bb - mu * scale;
}

// async global->LDS, 16B/lane: wave-uniform base + lane*16.
static __device__ __forceinline__ void stage16(const void* g, void* ldsBase, int lane) {
#if __has_builtin(__builtin_amdgcn_global_load_lds)
    __builtin_amdgcn_global_load_lds(
        (const __attribute__((address_space(1))) unsigned int*)(uintptr_t)g,
        (__attribute__((address_space(3))) unsigned int*)(unsigned int)(uintptr_t)ldsBase,
        16, 0, 0);
#else
    *(uint4*)((char*)ldsBase + lane * 16) = *(const uint4*)g;
#endif
}

// ---- W[t][I][O] fp32 -> WbT[t][Npad][Kpad] bf16, 64(i)x32(o) tile,
// vectorized: float4 reads, transposed LDS, uint4 writes. sm >= 32*72 shorts.
static __device__ __forceinline__ void cvt_w64(const float* Wt, unsigned short* dst,
                                               int I, int O, int Npad, int Kpad,
                                               int i0, int o0, int tid,
                                               unsigned short* sm) {
    const int TS = 72;   // tileT row stride (shorts); 144B = 16B-mult
    #pragma unroll
    for (int j = 0; j < 2; j++) {
        int u = tid + j * 256;               // 512 float4-units = 64 rows x 8
        int r = u >> 3, c4 = (u & 7) * 4;
        int i = i0 + r;
        float v0 = 0.f, v1 = 0.f, v2 = 0.f, v3 = 0.f;
        if (i < I) {
            const float* p = Wt + (size_t)i * O + o0 + c4;
            if (o0 + c4 + 4 <= O) {
                float4u v = *(const float4u*)p;
                v0 = v.x; v1 = v.y; v2 = v.z; v3 = v.w;
            } else {
                if (o0 + c4 + 0 < O) v0 = p[0];
                if (o0 + c4 + 1 < O) v1 = p[1];
                if (o0 + c4 + 2 < O) v2 = p[2];
                if (o0 + c4 + 3 < O) v3 = p[3];
            }
        }
        sm[(c4 + 0) * TS + r] = f2bf(v0);
        sm[(c4 + 1) * TS + r] = f2bf(v1);
        sm[(c4 + 2) * TS + r] = f2bf(v2);
        sm[(c4 + 3) * TS + r] = f2bf(v3);
    }
    __syncthreads();
    int o = tid >> 3, k8 = (tid & 7) * 8;
    int oo = o0 + o, kk = i0 + k8;
    if (oo < Npad && kk + 8 <= Kpad)
        *(uint4*)(dst + (size_t)oo * Kpad + kk) = *(const uint4*)(sm + o * TS + k8);
}

// ---- fused: x pack + W4..W1 cvt + W0 rows [512,1280) cvt + acc zeroing +
//      s4 per-chunk column stats (from x fp32 directly; bit-identical bf16) ----
#define PACK_BLOCKS ((BDIM * 512 + BDIM * 24 + 255) / 256)   // 4288
#define CVT_BLOCKS  1576                                      // 256+192+288+840
#define W0P1_BLOCKS (84 * 24)                                 // rows 512..1279
#define STATS_BLOCKS 1024
__global__ __launch_bounds__(256) void pack_cvt(const float* __restrict__ x,
                                                unsigned short* __restrict__ ain0,
                                                unsigned short* __restrict__ ain1,
                                                const float* __restrict__ W4,
                                                const float* __restrict__ W3,
                                                const float* __restrict__ W2,
                                                const float* __restrict__ W1,
                                                const float* __restrict__ W0,
                                                unsigned short* __restrict__ wbt,
                                                float* __restrict__ acc,
                                                const float* __restrict__ wbt4,  // bf16 W4 region (as ushort)
                                                const float* __restrict__ b4,
                                                float* __restrict__ sp4) {
    __shared__ __align__(16) unsigned short smem[64 * 168];   // stats xs / cvt tileT
    int bid = blockIdx.x;
    if (bid < 20) {   // zero the stat accumulators (s3..s0 regions)
        int idx = bid * 1024 + threadIdx.x * 4;
        *(float4*)(acc + idx) = make_float4(0.f, 0.f, 0.f, 0.f);
    }
    if (bid < PACK_BLOCKS) {
        const int MAIN = BDIM * 512;          // 8-float units
        int i = bid * 256 + threadIdx.x;
        if (i < MAIN) {
            int b = i >> 9, j = i & 511;
            const float* xp = x + (size_t)b * 4096 + j * 8;
            float4 lo = *(const float4*)xp, hi = *(const float4*)(xp + 4);
            union { unsigned short u[8]; uint4 v4; uint2 v2[2]; } t;
            t.u[0] = f2bf(lo.x); t.u[1] = f2bf(lo.y); t.u[2] = f2bf(lo.z); t.u[3] = f2bf(lo.w);
            t.u[4] = f2bf(hi.x); t.u[5] = f2bf(hi.y); t.u[6] = f2bf(hi.z); t.u[7] = f2bf(hi.w);
            *(uint4*)(ain0 + (size_t)b * 5376 + 1232 + j * 8) = t.v4;       // 16B aligned
            int gi = j * 8, tt = gi >> 10, u = gi & 1023;
            unsigned short* d1 = ain1 + (size_t)b * 5376 + tt * 1344 + 308 + u;  // 8B aligned
            *(uint2*)d1 = t.v2[0];
            *(uint2*)(d1 + 4) = t.v2[1];
            return;
        }
        int zi = i - MAIN;                    // zero pads, uint2 (4-short) units
        const int ZU = BDIM * 12;             // per-buffer zero units
        if (zi < ZU) {                        // ain0: cols [5328,5376)
            int b = zi / 12, u = zi % 12;
            *(uint2*)(ain0 + (size_t)b * 5376 + 5328 + u * 4) = make_uint2(0u, 0u);
        } else if (zi < 2 * ZU) {             // ain1: cols [t*1344+1332, +1344)
            zi -= ZU;
            int b = zi / 12, u = zi % 12, tt = u / 3, k = u % 3;
            *(uint2*)(ain1 + (size_t)b * 5376 + tt * 1344 + 1332 + k * 4) = make_uint2(0u, 0u);
        }
        return;
    }
    bid -= PACK_BLOCKS;
    if (bid < CVT_BLOCKS) {
        const float* W; unsigned short* dst;
        int I, O, Npad, Kpad, gx, gy, local;
        if (bid < 256)      { W = W4; dst = wbt;           I = 16;   O = 20;  Npad = 20;  Kpad = 32;   gx = 1;  gy = 1;  local = bid; }
        else if (bid < 448) { W = W3; dst = wbt + 163840;  I = 144;  O = 20;  Npad = 20;  Kpad = 192;  gx = 3;  gy = 1;  local = bid - 256; }
        else if (bid < 736) { W = W2; dst = wbt + 409600;  I = 336;  O = 77;  Npad = 77;  Kpad = 384;  gx = 6;  gy = 3;  local = bid - 448; }
        else                { W = W1; dst = wbt + 882688;  I = 1332; O = 308; Npad = 320; Kpad = 1344; gx = 21; gy = 10; local = bid - 736; }
        int per = gx * gy;
        int t = local / per, rem = local % per;
        int by = rem / gx, bx = rem % gx;
        cvt_w64(W + (size_t)t * I * O, dst + (size_t)t * Npad * Kpad,
                I, O, Npad, Kpad, bx * 64, by * 32, threadIdx.x, smem);
        return;
    }
    bid -= CVT_BLOCKS;
    if (bid < W0P1_BLOCKS) {                  // W0 part1: rows o>=512 (dst free at t=0)
        int bx = bid % 84, by = 16 + bid / 84;
        cvt_w64(W0, wbt, 5328, 1229, 1280, 5376, bx * 64, by * 32, threadIdx.x, smem);
        return;
    }
    bid -= W0P1_BLOCKS;
    // ---- s4 per-chunk stats from x fp32 (no dependency on pack output) ----
    {
        const int cg = bid & 31;
        const int rc = bid >> 5;
        const int t0 = cg * 8, b0 = rc * 64;
        const int tid = threadIdx.x;
        const int lane = tid & 63, w = tid >> 6;
        const int l15 = lane & 15, quad = lane >> 4;
        unsigned short (*xs)[168] = (unsigned short (*)[168])smem;
        const unsigned short* wb4 = (const unsigned short*)wbt4;

        #pragma unroll
        for (int j = 0; j < 8; j++) {
            int i = tid + j * 256;
            int r = i >> 5, gq = i & 31;          // 64 rows x 32 float4-granules
            float4 v = *(const float4*)(x + (size_t)(b0 + r) * 4096 + t0 * 16 + gq * 4);
            union { unsigned short u[4]; uint2 d; } o;
            o.u[0] = f2bf(v.x); o.u[1] = f2bf(v.y); o.u[2] = f2bf(v.z); o.u[3] = f2bf(v.w);
            *(uint2*)&xs[r][gq * 4] = o.d;
        }
        if (tid < 128) {
            int r = tid >> 1, gg = 16 + (tid & 1);
            *(uint4*)&xs[r][gg * 8] = make_uint4(0u, 0u, 0u, 0u);
        }
        __syncthreads();

        float4v acc4r[2][4][2];
        #pragma unroll
        for (int a = 0; a < 2; a++)
            #pragma unroll
            for (int b = 0; b < 4; b++)
                #pragma unroll
                for (int c = 0; c < 2; c++)
                    acc4r[a][b][c] = (float4v){0.f, 0.f, 0.f, 0.f};

        #pragma unroll
        for (int ti = 0; ti < 2; ti++) {
            const int lt = w * 2 + ti;
            const int t = t0 + lt;
            short8 bf[2];
            #pragma unroll
            for (int nf = 0; nf < 2; nf++)
                bf[nf] = *(const short8*)(wb4 + ((size_t)t * 20 + nf * 16 + l15) * 32 + quad * 8);
            #pragma unroll
            for (int mf = 0; mf < 4; mf++) {
                short8 a = *(const short8*)&xs[mf * 16 + l15][lt * 16 + quad * 8];
                #pragma unroll
                for (int nf = 0; nf < 2; nf++)
                    acc4r[ti][mf][nf] = __builtin_amdgcn_mfma_f32_16x16x32_bf16(a, bf[nf], acc4r[ti][mf][nf], 0, 0, 0);
            }
        }

        #pragma unroll
        for (int ti = 0; ti < 2; ti++) {
            const int lt = w * 2 + ti;
            #pragma unroll
            for (int nf = 0; nf < 2; nf++) {
                const int o = nf * 16 + l15;
                const int col = (t0 + lt) * 20 + o;
                const bool valid = (o < 20);
                const float bias = valid ? b4[col] : 0.f;
                float s = 0.f, s2 = 0.f;
                #pragma unroll
                for (int mf = 0; mf < 4; mf++)
                    #pragma unroll
                    for (int r = 0; r < 4; r++) {
                        float v = acc4r[ti][mf][nf][r] + bias;
                        s += v; s2 += v * v;
                    }
                s  += __shfl_xor(s, 16, 64);  s  += __shfl_xor(s, 32, 64);
                s2 += __shfl_xor(s2, 16, 64); s2 += __shfl_xor(s2, 32, 64);
                if (quad == 0 && valid) {
                    sp4[(size_t)rc * 10240 + col] = s;
                    sp4[(size_t)rc * 10240 + 5120 + col] = s2;
                }
            }
        }
    }
}

// ---- s4+s3 fused (r20 de-serialized): parallel sp4 fold -> foldS; s4 MFMA;
// BN(inline from foldS)+tanh -> act in LDS + headL; coalesced s4 head out;
// s3 MFMA -> h3 + atomic col stats -> acc3.
__global__ __launch_bounds__(256) void s4s3_fused(
    const unsigned short* __restrict__ xg,   // genes, row stride 5376
    const unsigned short* __restrict__ wbt4, // [256][20][32]
    const unsigned short* __restrict__ wbt3, // [64][20][192]
    const float* __restrict__ b4,            // [5120]
    const float* __restrict__ sp4,           // [32][2][5120] chunk partials
    const float* __restrict__ g4,
    const float* __restrict__ bb4,
    const float* __restrict__ hw4,           // [5120]
    const float* __restrict__ hb4,           // [256]
    const float* __restrict__ b3,            // [1280]
    unsigned short* __restrict__ h3,         // [2048][1280]
    float* __restrict__ acc3,                // [2][1280] atomic accumulators
    float* __restrict__ out)
{
    const int cg = blockIdx.x & 31;
    const int rc = blockIdx.x >> 5;
    const int t0 = cg * 8, b0 = rc * 64;
    const int tid = threadIdx.x;
    const int lane = tid & 63, w = tid >> 6;
    const int l15 = lane & 15, quad = lane >> 4;

    __shared__ __align__(16) unsigned short gs[64][152];
    __shared__ __align__(16) unsigned short as_[64][168];
    __shared__ float foldS[320];     // [stat][160] raw column sums
    __shared__ float headL[64][8];   // s4 head partials (raw, hb added at store)

    // gs staging first (HBM latency) ...
    #pragma unroll
    for (int j = 0; j < 4; j++) {
        int i = tid + j * 256;
        int r = i >> 4, gg = i & 15;
        *(uint4*)&gs[r][gg * 8] =
            *(const uint4*)(xg + (size_t)(b0 + r) * 5376 + t0 * 16 + gg * 8);
    }
    if (tid < 128) {
        int r = tid >> 1, gg = 16 + (tid & 1);
        *(uint4*)&gs[r][gg * 8] = make_uint4(0u, 0u, 0u, 0u);
    }
    // ... then L2-hot parallel fold (latencies overlap). 320 units, all threads.
    for (int u = tid; u < 320; u += 256) {
        const int st = (u >= 160) ? 1 : 0;
        const int cl = u - st * 160;
        const float* p = sp4 + (size_t)st * 5120 + t0 * 20 + cl;
        float a0 = 0.f, a1 = 0.f, a2 = 0.f, a3 = 0.f;
        #pragma unroll
        for (int ch = 0; ch < 32; ch += 4) {
            a0 += p[(size_t)(ch + 0) * 10240];
            a1 += p[(size_t)(ch + 1) * 10240];
            a2 += p[(size_t)(ch + 2) * 10240];
            a3 += p[(size_t)(ch + 3) * 10240];
        }
        foldS[u] = (a0 + a1) + (a2 + a3);
    }
    __syncthreads();

    // ---- phase 1: s4 MFMA (identical order to stats pass)
    float4v acc[2][4][2];
    #pragma unroll
    for (int a = 0; a < 2; a++)
        #pragma unroll
        for (int b = 0; b < 4; b++)
            #pragma unroll
            for (int c = 0; c < 2; c++)
                acc[a][b][c] = (float4v){0.f, 0.f, 0.f, 0.f};

    #pragma unroll
    for (int ti = 0; ti < 2; ti++) {
        const int lt = w * 2 + ti;
        const int t = t0 + lt;
        short8 bf[2];
        #pragma unroll
        for (int nf = 0; nf < 2; nf++)
            bf[nf] = *(const short8*)(wbt4 + ((size_t)t * 20 + nf * 16 + l15) * 32 + quad * 8);
        #pragma unroll
        for (int mf = 0; mf < 4; mf++) {
            short8 a = *(const short8*)&gs[mf * 16 + l15][lt * 16 + quad * 8];
            #pragma unroll
            for (int nf = 0; nf < 2; nf++)
                acc[ti][mf][nf] = __builtin_amdgcn_mfma_f32_16x16x32_bf16(a, bf[nf], acc[ti][mf][nf], 0, 0, 0);
        }
    }

    // ---- phase 2: BN(inline from foldS)+tanh -> act into as_ + headL
    #pragma unroll
    for (int ti = 0; ti < 2; ti++) {
        const int lt = w * 2 + ti;
        float hp[4][4];
        #pragma unroll
        for (int mf = 0; mf < 4; mf++)
            #pragma unroll
            for (int r = 0; r < 4; r++) hp[mf][r] = 0.f;
        #pragma unroll
        for (int nf = 0; nf < 2; nf++) {
            const int o = nf * 16 + l15;
            const bool valid = (o < 20);
            float scale = 0.f, shp = 0.f, hwv = 0.f;
            if (valid) {
                const int lc = lt * 20 + o;
                const int col = t0 * 20 + lc;
                float sc, sh;
                bn_ss(foldS[lc], foldS[160 + lc], g4[col], bb4[col], sc, sh);
                scale = sc;
                shp = b4[col] * sc + sh;   // bias folded
                hwv = hw4[col];
            }
            #pragma unroll
            for (int mf = 0; mf < 4; mf++)
                #pragma unroll
                for (int r = 0; r < 4; r++) {
                    float av = fast_tanh(acc[ti][mf][nf][r] * scale + shp);
                    if (valid)
                        as_[mf * 16 + quad * 4 + r][lt * 20 + o] = f2bf(av);
                    hp[mf][r] += av * hwv;
                }
        }
        #pragma unroll
        for (int mf = 0; mf < 4; mf++)
            #pragma unroll
            for (int r = 0; r < 4; r++) {
                float v = hp[mf][r];
                v += __shfl_xor(v, 1, 64); v += __shfl_xor(v, 2, 64);
                v += __shfl_xor(v, 4, 64); v += __shfl_xor(v, 8, 64);
                if (l15 == 0)
                    headL[mf * 16 + quad * 4 + r][lt] = v;
            }
    }
    __syncthreads();   // as_ + headL fully written before s3 reads / head out

    // s4 head out: coalesced 8-float row segments (hb added here)
    #pragma unroll
    for (int u = tid; u < 512; u += 256) {
        int row = u >> 3, tc = u & 7;
        out[(size_t)(b0 + row) * OUTW + t0 + tc] = headL[row][tc] + hb4[t0 + tc];
    }

    // ---- phase 3: s3 MFMA
    const int t3l = w & 1, mh = w >> 1;
    const int t3 = cg * 2 + t3l;
    float4v acc3r[2][2];
    #pragma unroll
    for (int a = 0; a < 2; a++)
        #pragma unroll
        for (int b = 0; b < 2; b++)
            acc3r[a][b] = (float4v){0.f, 0.f, 0.f, 0.f};

    #pragma unroll
    for (int ks = 0; ks < 5; ks++) {
        const int k = ks * 32 + quad * 8;
        short8 bf[2];
        #pragma unroll
        for (int nf = 0; nf < 2; nf++)
            bf[nf] = *(const short8*)(wbt3 + ((size_t)t3 * 20 + nf * 16 + l15) * 192 + ks * 32 + quad * 8);
        #pragma unroll
        for (int mf2 = 0; mf2 < 2; mf2++) {
            const int row = (mh * 2 + mf2) * 16 + l15;
            const unsigned short* ap = (k < 80) ? &as_[row][t3l * 80 + k]
                                                : &gs[row][t3l * 64 + (k - 80)];
            short8 a = *(const short8*)ap;
            #pragma unroll
            for (int nf = 0; nf < 2; nf++)
                acc3r[mf2][nf] = __builtin_amdgcn_mfma_f32_16x16x32_bf16(a, bf[nf], acc3r[mf2][nf], 0, 0, 0);
        }
    }

    // ---- phase 4: h3 + atomic column stats -> acc3
    float ss_[2], ss2_[2];
    #pragma unroll
    for (int nf = 0; nf < 2; nf++) { ss_[nf] = 0.f; ss2_[nf] = 0.f; }
    #pragma unroll
    for (int mf2 = 0; mf2 < 2; mf2++)
        #pragma unroll
        for (int nf = 0; nf < 2; nf++) {
            const int o = nf * 16 + l15;
            const int col = t3 * 20 + o;
            const bool valid = (o < 20);
            const float bias = valid ? b3[col] : 0.f;
            #pragma unroll
            for (int r = 0; r < 4; r++) {
                const int m = (mh * 2 + mf2) * 16 + quad * 4 + r;
                float v = acc3r[mf2][nf][r] + bias;
                if (valid)
                    h3[(size_t)(b0 + m) * 1280 + col] = f2bf(v);
                ss_[nf] += v; ss2_[nf] += v * v;
            }
        }
    #pragma unroll
    for (int nf = 0; nf < 2; nf++) {
        ss_[nf]  += __shfl_xor(ss_[nf], 16, 64);  ss_[nf]  += __shfl_xor(ss_[nf], 32, 64);
        ss2_[nf] += __shfl_xor(ss2_[nf], 16, 64); ss2_[nf] += __shfl_xor(ss2_[nf], 32, 64);
        const int o = nf * 16 + l15;
        if (quad == 0 && o < 20) {
            const int col = t3 * 20 + o;
            atomicAdd(acc3 + col, ss_[nf]);
            atomicAdd(acc3 + 1280 + col, ss2_[nf]);
        }
    }
}

// ---- s2 GEMM + on-the-fly act3 (BN+tanh from acc3) + s3 head + s2 stats ----
__global__ __launch_bounds__(256) void s2_fused(
    const unsigned short* __restrict__ h3,    // [2048][1280] bf16 (raw pre-BN)
    const unsigned short* __restrict__ xg,    // bf16 x copy, row stride 5376
    const unsigned short* __restrict__ WbT,   // s2 region: [16][77][384]
    const float* __restrict__ acc3,           // [2][1280] s3 stats (complete)
    const float* __restrict__ g3, const float* __restrict__ bb3,
    const float* __restrict__ hw3, const float* __restrict__ hb3,
    const float* __restrict__ b2,
    unsigned short* __restrict__ h,           // [2048][1232]
    float* __restrict__ acc2,                 // [2][1232] atomic accumulators
    float* __restrict__ out)
{
    constexpr int BN = 96, BK = 64;
    constexpr int I = 336, O = 77, C = 80, Gs = 256, Kpad = 384;
    constexpr int hstride = 1232, TO = 1232;
    const int t  = blockIdx.z;
    const int b0 = blockIdx.y * 64;
    const int tid = threadIdx.x;
    const int lane = tid & 63;
    const int w = tid >> 6;
    const int l15 = lane & 15;
    const int quad = lane >> 4;

    constexpr int NF = BN / 32;               // 3
    const int wm = (w & 1) * 32;
    const int wn = (w >> 1) * (BN / 2);       // 0 / 48

    __shared__ __align__(16) unsigned short As[64][BK + 8];
    __shared__ __align__(16) unsigned short Bs[BN][BK + 8];
    __shared__ float ldsS[2][BN], ldsS2[2][BN];
    __shared__ float scL[80], shL[80], hwL[80];
    __shared__ float headAcc[64][4];

    if (tid < 80) {
        int col = t * 80 + tid;
        float sc, sh;
        bn_ss(acc3[col], acc3[1280 + col], g3[col], bb3[col], sc, sh);
        scL[tid] = sc; shL[tid] = sh; hwL[tid] = hw3[col];
    }
    headAcc[tid >> 2][tid & 3] = 0.f;
    __syncthreads();

    float4v accr[2][NF];
    #pragma unroll
    for (int a = 0; a < 2; a++)
        #pragma unroll
        for (int b = 0; b < NF; b++)
            accr[a][b] = (float4v){0.f, 0.f, 0.f, 0.f};

    constexpr int GR = BK / 8;     // 8
    constexpr int AG = 64 * GR;    // 512
    constexpr int BG = BN * GR;    // 768

    for (int k0 = 0; k0 < Kpad; k0 += BK) {
        #pragma unroll
        for (int g = tid; g < AG; g += 256) {
            const int r = g / GR, c8 = g % GR;
            const int k = k0 + c8 * 8;
            const int b = b0 + r;
            if (k + 8 <= C) {
                union { unsigned short u[8]; uint4 v; } hi_, ho;
                hi_.v = *(const uint4*)(h3 + (size_t)b * 1280 + t * 80 + k);
                const int tA = k / 20, tB = (k + 7) / 20;
                float pA = 0.f, pB = 0.f;
                #pragma unroll
                for (int j = 0; j < 8; j++) {
                    const int kk = k + j;
                    float av = fast_tanh(bf2f(hi_.u[j]) * scL[kk] + shL[kk]);
                    ho.u[j] = f2bf(av);
                    float pr = av * hwL[kk];
                    if (kk / 20 == tA) pA += pr; else pB += pr;
                }
                atomicAdd(&headAcc[r][tA], pA);
                if (tB != tA) atomicAdd(&headAcc[r][tB], pB);
                *(uint4*)&As[r][c8 * 8] = ho.v;
            } else if (k >= I) {
                *(uint4*)&As[r][c8 * 8] = make_uint4(0u, 0u, 0u, 0u);
            } else {
                *(uint4*)&As[r][c8 * 8] =
                    *(const uint4*)(xg + (size_t)b * 5376 + t * Gs + (k - C));
            }
        }
        #pragma unroll
        for (int g = tid; g < BG; g += 256) {
            const int n = g / GR, c8 = g % GR;
            uint4 v = make_uint4(0u, 0u, 0u, 0u);
            if (n < O)
                v = *(const uint4*)(WbT + ((size_t)t * O + n) * Kpad + k0 + c8 * 8);
            *(uint4*)&Bs[n][c8 * 8] = v;
        }
        __syncthreads();
        #pragma unroll
        for (int ks = 0; ks < BK / 32; ks++) {
            const int koff = ks * 32 + quad * 8;
            short8 a0 = *(const short8*)&As[wm + l15][koff];
            short8 a1 = *(const short8*)&As[wm + 16 + l15][koff];
            #pragma unroll
            for (int fn = 0; fn < NF; fn++) {
                short8 bf = *(const short8*)&Bs[wn + fn * 16 + l15][koff];
                accr[0][fn] = __builtin_amdgcn_mfma_f32_16x16x32_bf16(a0, bf, accr[0][fn], 0, 0, 0);
                accr[1][fn] = __builtin_amdgcn_mfma_f32_16x16x32_bf16(a1, bf, accr[1][fn], 0, 0, 0);
            }
        }
        __syncthreads();
    }

    // s3 head out
    {
        const int r = tid >> 2, t3l = tid & 3;
        const int t3 = t * 4 + t3l;
        out[(size_t)(b0 + r) * OUTW + 256 + t3] = headAcc[r][t3l] + hb3[t3];
    }

    // epilogue + per-thread column partial sums (fp32, pre-rounding)
    float csum[NF], csum2[NF];
    #pragma unroll
    for (int fn = 0; fn < NF; fn++) { csum[fn] = 0.f; csum2[fn] = 0.f; }
    #pragma unroll
    for (int fm = 0; fm < 2; fm++)
        #pragma unroll
        for (int fn = 0; fn < NF; fn++)
            #pragma unroll
            for (int r = 0; r < 4; r++) {
                int m = wm + fm * 16 + quad * 4 + r;
                int o = wn + fn * 16 + l15;
                if (o < O) {
                    float v = accr[fm][fn][r] + b2[t * O + o];
                    h[(size_t)(b0 + m) * hstride + (size_t)t * O + o] = f2bf(v);
                    csum[fn] += v; csum2[fn] += v * v;
                }
            }
    #pragma unroll
    for (int fn = 0; fn < NF; fn++) {
        csum[fn]  += __shfl_xor(csum[fn], 16, 64);
        csum[fn]  += __shfl_xor(csum[fn], 32, 64);
        csum2[fn] += __shfl_xor(csum2[fn], 16, 64);
        csum2[fn] += __shfl_xor(csum2[fn], 32, 64);
    }
    if (quad == 0) {
        #pragma unroll
        for (int fn = 0; fn < NF; fn++) {
            ldsS[w & 1][wn + fn * 16 + l15]  = csum[fn];
            ldsS2[w & 1][wn + fn * 16 + l15] = csum2[fn];
        }
    }
    __syncthreads();
    if (tid < BN && tid < O) {
        int col = t * O + tid;
        atomicAdd(acc2 + col,      ldsS[0][tid] + ldsS[1][tid]);
        atomicAdd(acc2 + TO + col, ldsS2[0][tid] + ldsS2[1][tid]);
    }
}

// ---- big-stage GEMM (s1/s0): 128-row tile, BK=32, dbuf LDS, XCD-swizzled 1D grid
// (round-8 proven body, FROZEN -- r9/r10/r11/r16 all regressed).
template <int BN>
__global__ __launch_bounds__(256) void gemm_split(
    const unsigned short* __restrict__ A,     // [2048][aStride] bf16 (zero-padded)
    const unsigned short* __restrict__ WbT,   // [T][Npad][Kpad] bf16 (zero-padded)
    float* __restrict__ partial,              // [KS][2048][TNpad]
    int aStride, int tStride, int Kpad, int Npad, int KS, int TNpad,
    int nTiles, int TKS)
{
    const int tid = threadIdx.x;
    const int lane = tid & 63, w = tid >> 6;
    const int l15 = lane & 15, quad = lane >> 4;

    // swizzled decode
    const int id = blockIdx.x;
    const int c = id & 7;
    const int tmp = id >> 3;
    const int n = tmp % nTiles;
    const int q = tmp / nTiles;
    const int group = q * 8 + c;
    const int b0 = (group / TKS) * 128;
    const int rem = group % TKS;
    const int t = rem / KS;
    const int ksIdx = rem - t * KS;
    const int n0 = n * BN;

    __shared__ __align__(16) unsigned short As[2][128 * 32];   // 2 x 8 KB
    __shared__ __align__(16) unsigned short Bs[2][BN * 32];    // 2 x 8/4 KB

    const int S = Kpad >> 5;
    const int qb = S / KS, rb = S % KS;
    const int beg = ksIdx * qb + (ksIdx < rb ? ksIdx : rb);
    const int cnt = qb + (ksIdx < rb ? 1 : 0);

    constexpr int NF = BN / 32;
    const int wm = (w & 1) * 64;
    const int wn = (w >> 1) * (BN / 2);

    float4v acc[4][NF];
    #pragma unroll
    for (int a = 0; a < 4; a++)
        #pragma unroll
        for (int b = 0; b < NF; b++)
            acc[a][b] = (float4v){0.f, 0.f, 0.f, 0.f};

    // A staging: 512 granule-slots, 2 calls/wave
    const unsigned short* aSrc[2];
    int aOff[2];
    #pragma unroll
    for (int j = 0; j < 2; j++) {
        int s = (w * 2 + j) * 64 + lane;
        int r = s >> 2, kg = (s & 3) ^ ((r >> 1) & 3);
        aSrc[j] = A + (size_t)(b0 + r) * aStride + (size_t)t * tStride + kg * 8;
        aOff[j] = (w * 2 + j) * 512;           // shorts
    }
    // B staging
    constexpr int BCALLS = (BN == 128) ? 2 : 1;
    const unsigned short* bSrc[BCALLS];
    int bOff[BCALLS];
    #pragma unroll
    for (int j = 0; j < BCALLS; j++) {
        int s = (w * BCALLS + j) * 64 + lane;
        int r = s >> 2, kg = (s & 3) ^ ((r >> 1) & 3);
        bSrc[j] = WbT + ((size_t)t * Npad + n0 + r) * Kpad + kg * 8;
        bOff[j] = (w * BCALLS + j) * 512;
    }

    // prologue: stage step 0 into buf 0
    {
        const int k0 = beg << 5;
        #pragma unroll
        for (int j = 0; j < 2; j++)      stage16(aSrc[j] + k0, &As[0][aOff[j]], lane);
        #pragma unroll
        for (int j = 0; j < BCALLS; j++) stage16(bSrc[j] + k0, &Bs[0][bOff[j]], lane);
    }

    for (int s = 0; s < cnt; s++) {
        const int cur = s & 1;
        __syncthreads();   // drains cur-buf loads (in flight since prev iter) + prev compute
        if (s + 1 < cnt) {
            const int k1 = (beg + s + 1) << 5;
            #pragma unroll
            for (int j = 0; j < 2; j++)      stage16(aSrc[j] + k1, &As[cur ^ 1][aOff[j]], lane);
            #pragma unroll
            for (int j = 0; j < BCALLS; j++) stage16(bSrc[j] + k1, &Bs[cur ^ 1][bOff[j]], lane);
        }
        short8 af[4];
        #pragma unroll
        for (int fm = 0; fm < 4; fm++) {
            int m = wm + fm * 16 + l15;
            int pos = quad ^ ((m >> 1) & 3);
            af[fm] = *(const short8*)&As[cur][(m * 4 + pos) * 8];
        }
        short8 bfr[NF];
        #pragma unroll
        for (int fn = 0; fn < NF; fn++) {
            int nn = wn + fn * 16 + l15;
            int pos = quad ^ ((nn >> 1) & 3);
            bfr[fn] = *(const short8*)&Bs[cur][(nn * 4 + pos) * 8];
        }
        #pragma unroll
        for (int fm = 0; fm < 4; fm++)
            #pragma unroll
            for (int fn = 0; fn < NF; fn++)
                acc[fm][fn] = __builtin_amdgcn_mfma_f32_16x16x32_bf16(af[fm], bfr[fn], acc[fm][fn], 0, 0, 0);
    }

    const size_t pBase = ((size_t)ksIdx * BDIM + b0) * TNpad + (size_t)t * Npad + n0;
    #pragma unroll
    for (int fm = 0; fm < 4; fm++)
        #pragma unroll
        for (int r = 0; r < 4; r++) {
            const int m = wm + fm * 16 + quad * 4 + r;
            float* prow = partial + pBase + (size_t)m * TNpad + wn;
            #pragma unroll
            for (int fn = 0; fn < NF; fn++)
                prow[fn * 16 + l15] = acc[fm][fn][r];
        }
}

// ---- s1 split-K reduce + W0 rows [0,512) cvt, one launch (flat grid) ----
__global__ __launch_bounds__(256) void reduce1_cvtw0(
    const float* __restrict__ partial, const float* __restrict__ bias,
    unsigned short* __restrict__ h, float* __restrict__ acc,
    const float* __restrict__ W0, unsigned short* __restrict__ wbt)
{
    __shared__ __align__(16) unsigned short tile[32 * 72];
    const int bid = blockIdx.x;
    if (bid >= 320) {
        int local = bid - 320;
        int bx = local % 84, by = local / 84;   // by in [0,16)
        cvt_w64(W0, wbt, 5328, 1229, 1280, 5376, bx * 64, by * 32, threadIdx.x, tile);
        return;
    }
    constexpr int T = 4, O = 308, Npad = 320, KS = 2, hstride = 1232, TO = 1232;
    __shared__ float redS[4][64], redS2[4][64];
    const int colL = threadIdx.x & 63;
    const int cr = threadIdx.x >> 6;
    const int col = (bid % 20) * 64 + colL;
    const int chunk = bid / 20;
    float s = 0.f, s2 = 0.f;
    if (col < TO) {
        int t = col / O, o = col - t * O;
        const size_t TNpad = (size_t)T * Npad;
        const size_t pcol = (size_t)t * Npad + o;
        const float bv = bias[col];
        const int row0 = chunk * 128 + cr * 32;
        for (int r = 0; r < 32; r++) {
            const int row = row0 + r;
            const float* p = partial + (size_t)row * TNpad + pcol;
            float v = bv;
            for (int ks = 0; ks < KS; ks++) v += p[(size_t)ks * BDIM * TNpad];
            h[(size_t)row * hstride + col] = f2bf(v);
            s += v; s2 += v * v;
        }
    }
    redS[cr][colL] = s; redS2[cr][colL] = s2;
    __syncthreads();
    if (cr == 0 && col < TO) {
        float ts  = redS[0][colL] + redS[1][colL] + redS[2][colL] + redS[3][colL];
        float ts2 = redS2[0][colL] + redS2[1][colL] + redS2[2][colL] + redS2[3][colL];
        atomicAdd(acc + col, ts);
        atomicAdd(acc + TO + col, ts2);
    }
}

// ---- s0 split-K reduce, VECTORIZED (r19): grid dim3(5,128); thread = 4 cols
// (float4) x 4 rows; wave reads 1KB contiguous per (row,ks). h uint2 stores.
__global__ __launch_bounds__(256) void reduce0_vec(
    const float* __restrict__ partial, const float* __restrict__ bias,
    unsigned short* __restrict__ h, float* __restrict__ acc)
{
    constexpr int Npad = 1280, KS = 4, hstride = 1232, O = 1229;
    const int tid = threadIdx.x;
    const int lane = tid & 63, wv = tid >> 6;
    const int c4 = blockIdx.x * 256 + lane * 4;
    const int row0 = blockIdx.y * 16 + wv * 4;
    __shared__ float redS[4][256], redS2[4][256];

    float4 bv = make_float4(0.f, 0.f, 0.f, 0.f);
    if (c4 + 4 <= O) {
        bv = *(const float4*)(bias + c4);
    } else {
        if (c4 + 0 < O) bv.x = bias[c4 + 0];
        if (c4 + 1 < O) bv.y = bias[c4 + 1];
        if (c4 + 2 < O) bv.z = bias[c4 + 2];
        if (c4 + 3 < O) bv.w = bias[c4 + 3];
    }

    float s0 = 0.f, s1 = 0.f, s2 = 0.f, s3 = 0.f;
    float q0 = 0.f, q1 = 0.f, q2 = 0.f, q3 = 0.f;
    #pragma unroll
    for (int r = 0; r < 4; r++) {
        const int row = row0 + r;
        const float* p = partial + (size_t)row * Npad + c4;
        float4 v = bv;
        #pragma unroll
        for (int ks = 0; ks < KS; ks++) {
            float4 pv = *(const float4*)(p + (size_t)ks * BDIM * Npad);
            v.x += pv.x; v.y += pv.y; v.z += pv.z; v.w += pv.w;
        }
        if (c4 + 4 <= hstride) {
            union { unsigned short u[4]; uint2 d; } o;
            o.u[0] = f2bf(v.x); o.u[1] = f2bf(v.y); o.u[2] = f2bf(v.z); o.u[3] = f2bf(v.w);
            *(uint2*)(h + (size_t)row * hstride + c4) = o.d;
        }
        s0 += v.x; s1 += v.y; s2 += v.z; s3 += v.w;
        q0 += v.x * v.x; q1 += v.y * v.y; q2 += v.z * v.z; q3 += v.w * v.w;
    }
    const int ci = lane * 4;
    redS[wv][ci + 0] = s0; redS[wv][ci + 1] = s1; redS[wv][ci + 2] = s2; redS[wv][ci + 3] = s3;
    redS2[wv][ci + 0] = q0; redS2[wv][ci + 1] = q1; redS2[wv][ci + 2] = q2; redS2[wv][ci + 3] = q3;
    __syncthreads();
    {
        const int col = blockIdx.x * 256 + tid;
        if (col < O) {
            float ts  = redS[0][tid] + redS[1][tid] + redS[2][tid] + redS[3][tid];
            float tq  = redS2[0][tid] + redS2[1][tid] + redS2[2][tid] + redS2[3][tid];
            atomicAdd(acc + col, ts);
            atomicAdd(acc + O + col, tq);
        }
    }
}

// ---- BN(from acc) + tanh + strided act store + head — WAVE variant ----
__global__ __launch_bounds__(256) void bn_tanh_head(
    const unsigned short* __restrict__ h, const float* __restrict__ acc,
    const float* __restrict__ g, const float* __restrict__ bb,
    const float* __restrict__ hw, const float* __restrict__ hb,
    unsigned short* __restrict__ actOut, float* __restrict__ out,
    int T, int O, int hstride, int aRow, int GT, int GS, int head_off, int TO)
{
    int wid  = (blockIdx.x * 256 + threadIdx.x) >> 6;
    int lane = threadIdx.x & 63;
    int b = wid / T;
    int t = wid % T;
    const size_t hbase = (size_t)b * hstride + (size_t)t * O;
    const size_t abase = (size_t)b * aRow + (size_t)(t / GT) * GS + (size_t)(t % GT) * O;
    float hsum = 0.f;
    for (int o = lane; o < O; o += 64) {
        int col = t * O + o;
        float sc, sh;
        bn_ss(acc[col], acc[TO + col], g[col], bb[col], sc, sh);
        float a = fast_tanh(bf2f(h[hbase + o]) * sc + sh);
        if (actOut) actOut[abase + o] = f2bf(a);
        hsum += a * hw[col];
    }
    #pragma unroll
    for (int off = 32; off > 0; off >>= 1) hsum += __shfl_down(hsum, off, 64);
    if (lane == 0) out[(size_t)b * OUTW + head_off + t] = hsum + hb[t];
}

extern "C" void kernel_launch(void* const* d_in, const int* in_sizes, int n_in,
                              void* d_out, int out_size, void* d_ws, size_t ws_size,
                              hipStream_t stream)
{
    const float* x = (const float*)d_in[0];
    float* out = (float*)d_out;
    char* ws = (char*)d_ws;

    // ws layout (bytes)
    unsigned short* wbt  = (unsigned short*)(ws);              // 13,762,560
    unsigned short* ain0 = (unsigned short*)(ws + 13762560);   // 22,020,096 (2048x5376)
    unsigned short* bufB = (unsigned short*)(ws + 56754176);   //  5,242,880
    unsigned short* ain1 = (unsigned short*)(ws + 61997056);   // 22,020,096
    unsigned short* bufC = (unsigned short*)(ws + 84017152);   //  5,046,272
    float*          accB = (float*)(ws + 89063424);            //  81 KB stat accumulators
    // overlays (all verified dead at use time):
    float* partial = (float*)(ws + 35782656);   // s1: 21 MB, s0: 41.9 MB (dead regions)
    unsigned short* xg = ain0 + 1232;           // full bf16 x copy, row stride 5376
    float* sp4 = (float*)bufC;                  // 32x2x5120x4 = 1.31 MB (bufC dead until s2_fused h2)
    // per-stage atomic stat accumulators (sum[TO] then sumsq[TO]):
    float* acc3 = accB + 10240;    // 2x1280
    float* acc2 = accB + 12800;    // 2x1232
    float* acc1 = accB + 15264;    // 2x1232
    float* acc0 = accB + 17728;    // 2x1229

    const float* W4 = (const float*)d_in[1];  const float* b4 = (const float*)d_in[2];
    const float* g4 = (const float*)d_in[3];  const float* bb4 = (const float*)d_in[4];
    const float* hw4 = (const float*)d_in[5]; const float* hb4 = (const float*)d_in[6];
    const float* W3 = (const float*)d_in[7];  const float* b3 = (const float*)d_in[8];
    const float* g3 = (const float*)d_in[9];  const float* bb3 = (const float*)d_in[10];
    const float* hw3 = (const float*)d_in[11]; const float* hb3 = (const float*)d_in[12];
    const float* W2 = (const float*)d_in[13]; const float* b2 = (const float*)d_in[14];
    const float* g2 = (const float*)d_in[15]; const float* bb2 = (const float*)d_in[16];
    const float* hw2 = (const float*)d_in[17]; const float* hb2 = (const float*)d_in[18];
    const float* W1 = (const float*)d_in[19]; const float* b1 = (const float*)d_in[20];
    const float* g1 = (const float*)d_in[21]; const float* bb1 = (const float*)d_in[22];
    const float* hw1 = (const float*)d_in[23]; const float* hb1 = (const float*)d_in[24];
    const float* W0 = (const float*)d_in[25]; const float* b0_ = (const float*)d_in[26];
    const float* g0 = (const float*)d_in[27]; const float* bb0 = (const float*)d_in[28];
    const float* hw0 = (const float*)d_in[29]; const float* hb0 = (const float*)d_in[30];

    // 1: fused x pack + W cvts (vectorized) + acc zeroing + s4 chunk stats
    pack_cvt<<<PACK_BLOCKS + CVT_BLOCKS + W0P1_BLOCKS + STATS_BLOCKS, 256, 0, stream>>>(
        x, ain0, ain1, W4, W3, W2, W1, W0, wbt, accB, (const float*)wbt, b4, sp4);

    // 2: s4 act recompute (parallel fold) + s3 GEMM: h3 -> bufB, stats -> acc3
    s4s3_fused<<<1024, 256, 0, stream>>>(xg, wbt, wbt + 163840, b4, sp4, g4, bb4,
                                         hw4, hb4, b3, bufB, acc3, out);

    // 3: s2 GEMM with on-the-fly act3 + s3 head + s2 stats (h2 -> bufC)
    s2_fused<<<dim3(1, 32, 16), 256, 0, stream>>>(bufB, xg, wbt + 409600, acc3,
                                                  g3, bb3, hw3, hb3, b2,
                                                  bufC, acc2, out);
    // 4: s2 BN+tanh -> act2 (ain1) + s2 head
    bn_tanh_head<<<BDIM * 16 / 4, 256, 0, stream>>>(bufC, acc2, g2, bb2, hw2, hb2,
                                                    ain1, out, 16, 77, 1232, 5376, 4, 1344, 320, 1232);

    // 5: s1 GEMM (T=4 I=1332 O=308 Kpad=1344 Npad=320 KS=2, WbT @882688)
    gemm_split<64><<<640, 256, 0, stream>>>(ain1, wbt + 882688, partial,
                                            5376, 1344, 1344, 320, 2, 1280, 5, 8);
    // 6: s1 reduce + W0 rows [0,512) cvt (h1 -> bufC)
    reduce1_cvtw0<<<320 + 84 * 16, 256, 0, stream>>>(partial, b1, bufC, acc1, W0, wbt);
    // 7: s1 BN+tanh -> act1 (ain0) + s1 head
    bn_tanh_head<<<BDIM * 4 / 4, 256, 0, stream>>>(bufC, acc1, g1, bb1, hw1, hb1,
                                                   ain0, out, 4, 308, 1232, 5376, 4, 0, 336, 1232);

    // 8: s0 GEMM (T=1 I=5328 O=1229 Kpad=5376 Npad=1280 KS=4)
    gemm_split<128><<<640, 256, 0, stream>>>(ain0, wbt, partial,
                                             5376, 0, 5376, 1280, 4, 1280, 10, 4);
    // 9: s0 reduce, vectorized (h0 -> bufC)
    reduce0_vec<<<dim3(5, 128), 256, 0, stream>>>(partial, b0_, bufC, acc0);
    // 10: s0 BN+tanh+head
    bn_tanh_head<<<BDIM / 4, 256, 0, stream>>>(bufC, acc0, g0, bb0, hw0, hb0,
                                               nullptr, out, 1, 1229, 1232, 1232, 1, 0, 340, 1229);
}

// Round 14
// 333.591 us; speedup vs baseline: 1.0156x; 1.0156x over previous
//
#include <hip/hip_runtime.h>
#include <hip/hip_bf16.h>

// DCell forward, bf16-MFMA. Round-22 = REVERT to round-19 (best measured:
// 334.8us). Round-21's cooperative tail-collapse FAILED correctness --
// hipLaunchCooperativeKernel does not survive the harness's graph capture
// (s1/s0 head region garbage). Lesson: the 9 remaining launch boundaries
// each carry a true cross-XCD visibility flush; a software grid barrier
// pays the same L2-drain (r10) even when it works. Dispatch-count lever is
// exhausted at 10.
//  * reduce0_vec (r19): wide-grid vectorized s0 reduce.
//  * cvt_w64 (r18): vectorized W conversion.
//  * stats-in-pack (r17), s4s3/s2 fusions (r13/r15), atomic stats (r14).
//  * gemm_split round-8 body FROZEN (r9/r10/r11/r16 all regressed).
// Stage cfg (T,I,O,C,Gs): s4(256,16,20,0,16) s3(64,144,20,80,64)
//  s2(16,336,77,80,256) s1(4,1332,308,308,1024) s0(1,5328,1229,1232,4096)

#define BDIM 2048
#define OUTW 341

typedef __attribute__((ext_vector_type(8))) short short8;
typedef __attribute__((ext_vector_type(4))) float float4v;
typedef float float4u __attribute__((ext_vector_type(4), aligned(4)));   // 4B-aligned load

static __device__ __forceinline__ unsigned short f2bf(float f) {
    union { float f; unsigned u; } c{f};
    unsigned r = c.u + 0x7FFF + ((c.u >> 16) & 1);  // RNE
    return (unsigned short)(r >> 16);
}
static __device__ __forceinline__ float bf2f(unsigned short s) {
    union { unsigned u; float f; } c{(unsigned)s << 16};
    return c.f;
}

static __device__ __forceinline__ float fast_tanh(float x) {
    float ax = __builtin_fabsf(x);
    float e  = __builtin_amdgcn_exp2f(ax * 2.8853900817779268f);  // e^{2|x|}
    float r  = 1.f - 2.f * __builtin_amdgcn_rcpf(e + 1.f);
    return __builtin_copysignf(r, x);
}

// scale/shift from accumulated (sum, sumsq): identical expression everywhere.
static __device__ __forceinline__ void bn_ss(float sm, float sq, float g, float bb,
                                             float& scale, float& shift) {
    float mu = sm * (1.f / BDIM);
    float var = sq * (1.f / BDIM) - mu * mu;  // biased, matches jnp.var
    scale = rsqrtf(var + 1e-5f) * g;
    shift = bb - mu * scale;
}

// async global->LDS, 16B/lane: wave-uniform base + lane*16.
static __device__ __forceinline__ void stage16(const void* g, void* ldsBase, int lane) {
#if __has_builtin(__builtin_amdgcn_global_load_lds)
    __builtin_amdgcn_global_load_lds(
        (const __attribute__((address_space(1))) unsigned int*)(uintptr_t)g,
        (__attribute__((address_space(3))) unsigned int*)(unsigned int)(uintptr_t)ldsBase,
        16, 0, 0);
#else
    *(uint4*)((char*)ldsBase + lane * 16) = *(const uint4*)g;
#endif
}

// ---- W[t][I][O] fp32 -> WbT[t][Npad][Kpad] bf16, 64(i)x32(o) tile,
// vectorized: float4 reads, transposed LDS, uint4 writes. sm >= 32*72 shorts.
static __device__ __forceinline__ void cvt_w64(const float* Wt, unsigned short* dst,
                                               int I, int O, int Npad, int Kpad,
                                               int i0, int o0, int tid,
                                               unsigned short* sm) {
    const int TS = 72;   // tileT row stride (shorts); 144B = 16B-mult
    #pragma unroll
    for (int j = 0; j < 2; j++) {
        int u = tid + j * 256;               // 512 float4-units = 64 rows x 8
        int r = u >> 3, c4 = (u & 7) * 4;
        int i = i0 + r;
        float v0 = 0.f, v1 = 0.f, v2 = 0.f, v3 = 0.f;
        if (i < I) {
            const float* p = Wt + (size_t)i * O + o0 + c4;
            if (o0 + c4 + 4 <= O) {
                float4u v = *(const float4u*)p;
                v0 = v.x; v1 = v.y; v2 = v.z; v3 = v.w;
            } else {
                if (o0 + c4 + 0 < O) v0 = p[0];
                if (o0 + c4 + 1 < O) v1 = p[1];
                if (o0 + c4 + 2 < O) v2 = p[2];
                if (o0 + c4 + 3 < O) v3 = p[3];
            }
        }
        sm[(c4 + 0) * TS + r] = f2bf(v0);
        sm[(c4 + 1) * TS + r] = f2bf(v1);
        sm[(c4 + 2) * TS + r] = f2bf(v2);
        sm[(c4 + 3) * TS + r] = f2bf(v3);
    }
    __syncthreads();
    int o = tid >> 3, k8 = (tid & 7) * 8;
    int oo = o0 + o, kk = i0 + k8;
    if (oo < Npad && kk + 8 <= Kpad)
        *(uint4*)(dst + (size_t)oo * Kpad + kk) = *(const uint4*)(sm + o * TS + k8);
}

// ---- fused: x pack + W4..W1 cvt + W0 rows [512,1280) cvt + acc zeroing +
//      s4 per-chunk column stats (from x fp32 directly; bit-identical bf16) ----
#define PACK_BLOCKS ((BDIM * 512 + BDIM * 24 + 255) / 256)   // 4288
#define CVT_BLOCKS  1576                                      // 256+192+288+840
#define W0P1_BLOCKS (84 * 24)                                 // rows 512..1279
#define STATS_BLOCKS 1024
__global__ __launch_bounds__(256) void pack_cvt(const float* __restrict__ x,
                                                unsigned short* __restrict__ ain0,
                                                unsigned short* __restrict__ ain1,
                                                const float* __restrict__ W4,
                                                const float* __restrict__ W3,
                                                const float* __restrict__ W2,
                                                const float* __restrict__ W1,
                                                const float* __restrict__ W0,
                                                unsigned short* __restrict__ wbt,
                                                float* __restrict__ acc,
                                                const float* __restrict__ wbt4,  // bf16 W4 region (as ushort)
                                                const float* __restrict__ b4,
                                                float* __restrict__ sp4) {
    __shared__ __align__(16) unsigned short smem[64 * 168];   // stats xs / cvt tileT
    int bid = blockIdx.x;
    if (bid < 20) {   // zero the stat accumulators (s3..s0 regions)
        int idx = bid * 1024 + threadIdx.x * 4;
        *(float4*)(acc + idx) = make_float4(0.f, 0.f, 0.f, 0.f);
    }
    if (bid < PACK_BLOCKS) {
        const int MAIN = BDIM * 512;          // 8-float units
        int i = bid * 256 + threadIdx.x;
        if (i < MAIN) {
            int b = i >> 9, j = i & 511;
            const float* xp = x + (size_t)b * 4096 + j * 8;
            float4 lo = *(const float4*)xp, hi = *(const float4*)(xp + 4);
            union { unsigned short u[8]; uint4 v4; uint2 v2[2]; } t;
            t.u[0] = f2bf(lo.x); t.u[1] = f2bf(lo.y); t.u[2] = f2bf(lo.z); t.u[3] = f2bf(lo.w);
            t.u[4] = f2bf(hi.x); t.u[5] = f2bf(hi.y); t.u[6] = f2bf(hi.z); t.u[7] = f2bf(hi.w);
            *(uint4*)(ain0 + (size_t)b * 5376 + 1232 + j * 8) = t.v4;       // 16B aligned
            int gi = j * 8, tt = gi >> 10, u = gi & 1023;
            unsigned short* d1 = ain1 + (size_t)b * 5376 + tt * 1344 + 308 + u;  // 8B aligned
            *(uint2*)d1 = t.v2[0];
            *(uint2*)(d1 + 4) = t.v2[1];
            return;
        }
        int zi = i - MAIN;                    // zero pads, uint2 (4-short) units
        const int ZU = BDIM * 12;             // per-buffer zero units
        if (zi < ZU) {                        // ain0: cols [5328,5376)
            int b = zi / 12, u = zi % 12;
            *(uint2*)(ain0 + (size_t)b * 5376 + 5328 + u * 4) = make_uint2(0u, 0u);
        } else if (zi < 2 * ZU) {             // ain1: cols [t*1344+1332, +1344)
            zi -= ZU;
            int b = zi / 12, u = zi % 12, tt = u / 3, k = u % 3;
            *(uint2*)(ain1 + (size_t)b * 5376 + tt * 1344 + 1332 + k * 4) = make_uint2(0u, 0u);
        }
        return;
    }
    bid -= PACK_BLOCKS;
    if (bid < CVT_BLOCKS) {
        const float* W; unsigned short* dst;
        int I, O, Npad, Kpad, gx, gy, local;
        if (bid < 256)      { W = W4; dst = wbt;           I = 16;   O = 20;  Npad = 20;  Kpad = 32;   gx = 1;  gy = 1;  local = bid; }
        else if (bid < 448) { W = W3; dst = wbt + 163840;  I = 144;  O = 20;  Npad = 20;  Kpad = 192;  gx = 3;  gy = 1;  local = bid - 256; }
        else if (bid < 736) { W = W2; dst = wbt + 409600;  I = 336;  O = 77;  Npad = 77;  Kpad = 384;  gx = 6;  gy = 3;  local = bid - 448; }
        else                { W = W1; dst = wbt + 882688;  I = 1332; O = 308; Npad = 320; Kpad = 1344; gx = 21; gy = 10; local = bid - 736; }
        int per = gx * gy;
        int t = local / per, rem = local % per;
        int by = rem / gx, bx = rem % gx;
        cvt_w64(W + (size_t)t * I * O, dst + (size_t)t * Npad * Kpad,
                I, O, Npad, Kpad, bx * 64, by * 32, threadIdx.x, smem);
        return;
    }
    bid -= CVT_BLOCKS;
    if (bid < W0P1_BLOCKS) {                  // W0 part1: rows o>=512 (dst free at t=0)
        int bx = bid % 84, by = 16 + bid / 84;
        cvt_w64(W0, wbt, 5328, 1229, 1280, 5376, bx * 64, by * 32, threadIdx.x, smem);
        return;
    }
    bid -= W0P1_BLOCKS;
    // ---- s4 per-chunk stats from x fp32 (no dependency on pack output) ----
    {
        const int cg = bid & 31;
        const int rc = bid >> 5;
        const int t0 = cg * 8, b0 = rc * 64;
        const int tid = threadIdx.x;
        const int lane = tid & 63, w = tid >> 6;
        const int l15 = lane & 15, quad = lane >> 4;
        unsigned short (*xs)[168] = (unsigned short (*)[168])smem;
        const unsigned short* wb4 = (const unsigned short*)wbt4;

        #pragma unroll
        for (int j = 0; j < 8; j++) {
            int i = tid + j * 256;
            int r = i >> 5, gq = i & 31;          // 64 rows x 32 float4-granules
            float4 v = *(const float4*)(x + (size_t)(b0 + r) * 4096 + t0 * 16 + gq * 4);
            union { unsigned short u[4]; uint2 d; } o;
            o.u[0] = f2bf(v.x); o.u[1] = f2bf(v.y); o.u[2] = f2bf(v.z); o.u[3] = f2bf(v.w);
            *(uint2*)&xs[r][gq * 4] = o.d;
        }
        if (tid < 128) {
            int r = tid >> 1, gg = 16 + (tid & 1);
            *(uint4*)&xs[r][gg * 8] = make_uint4(0u, 0u, 0u, 0u);
        }
        __syncthreads();

        float4v acc4r[2][4][2];
        #pragma unroll
        for (int a = 0; a < 2; a++)
            #pragma unroll
            for (int b = 0; b < 4; b++)
                #pragma unroll
                for (int c = 0; c < 2; c++)
                    acc4r[a][b][c] = (float4v){0.f, 0.f, 0.f, 0.f};

        #pragma unroll
        for (int ti = 0; ti < 2; ti++) {
            const int lt = w * 2 + ti;
            const int t = t0 + lt;
            short8 bf[2];
            #pragma unroll
            for (int nf = 0; nf < 2; nf++)
                bf[nf] = *(const short8*)(wb4 + ((size_t)t * 20 + nf * 16 + l15) * 32 + quad * 8);
            #pragma unroll
            for (int mf = 0; mf < 4; mf++) {
                short8 a = *(const short8*)&xs[mf * 16 + l15][lt * 16 + quad * 8];
                #pragma unroll
                for (int nf = 0; nf < 2; nf++)
                    acc4r[ti][mf][nf] = __builtin_amdgcn_mfma_f32_16x16x32_bf16(a, bf[nf], acc4r[ti][mf][nf], 0, 0, 0);
            }
        }

        #pragma unroll
        for (int ti = 0; ti < 2; ti++) {
            const int lt = w * 2 + ti;
            #pragma unroll
            for (int nf = 0; nf < 2; nf++) {
                const int o = nf * 16 + l15;
                const int col = (t0 + lt) * 20 + o;
                const bool valid = (o < 20);
                const float bias = valid ? b4[col] : 0.f;
                float s = 0.f, s2 = 0.f;
                #pragma unroll
                for (int mf = 0; mf < 4; mf++)
                    #pragma unroll
                    for (int r = 0; r < 4; r++) {
                        float v = acc4r[ti][mf][nf][r] + bias;
                        s += v; s2 += v * v;
                    }
                s  += __shfl_xor(s, 16, 64);  s  += __shfl_xor(s, 32, 64);
                s2 += __shfl_xor(s2, 16, 64); s2 += __shfl_xor(s2, 32, 64);
                if (quad == 0 && valid) {
                    sp4[(size_t)rc * 10240 + col] = s;
                    sp4[(size_t)rc * 10240 + 5120 + col] = s2;
                }
            }
        }
    }
}

// ---- s4+s3 fused: fold sp4 -> scale/shift (LDS), recompute s4 h -> BN+tanh
// -> act in LDS -> s4 head -> s3 MFMA -> h3 + atomic col stats -> acc3.
__global__ __launch_bounds__(256) void s4s3_fused(
    const unsigned short* __restrict__ xg,   // genes, row stride 5376
    const unsigned short* __restrict__ wbt4, // [256][20][32]
    const unsigned short* __restrict__ wbt3, // [64][20][192]
    const float* __restrict__ b4,            // [5120]
    const float* __restrict__ sp4,           // [32][2][5120] chunk partials
    const float* __restrict__ g4,
    const float* __restrict__ bb4,
    const float* __restrict__ hw4,           // [5120]
    const float* __restrict__ hb4,           // [256]
    const float* __restrict__ b3,            // [1280]
    unsigned short* __restrict__ h3,         // [2048][1280]
    float* __restrict__ acc3,                // [2][1280] atomic accumulators
    float* __restrict__ out)
{
    const int cg = blockIdx.x & 31;
    const int rc = blockIdx.x >> 5;
    const int t0 = cg * 8, b0 = rc * 64;
    const int tid = threadIdx.x;
    const int lane = tid & 63, w = tid >> 6;
    const int l15 = lane & 15, quad = lane >> 4;

    __shared__ __align__(16) unsigned short gs[64][152];
    __shared__ __align__(16) unsigned short as_[64][168];
    __shared__ float scP[160], shP[160], hwP[160];

    #pragma unroll
    for (int j = 0; j < 4; j++) {
        int i = tid + j * 256;
        int r = i >> 4, gg = i & 15;
        *(uint4*)&gs[r][gg * 8] =
            *(const uint4*)(xg + (size_t)(b0 + r) * 5376 + t0 * 16 + gg * 8);
    }
    if (tid < 128) {
        int r = tid >> 1, gg = 16 + (tid & 1);
        *(uint4*)&gs[r][gg * 8] = make_uint4(0u, 0u, 0u, 0u);
    }
    // fold 32 chunk partials -> scale/shift for this block's 160 columns
    if (tid < 160) {
        int col = t0 * 20 + tid;
        float s = 0.f, s2 = 0.f;
        for (int ch = 0; ch < 32; ch++) {
            s  += sp4[(size_t)ch * 10240 + col];
            s2 += sp4[(size_t)ch * 10240 + 5120 + col];
        }
        float sc, sh;
        bn_ss(s, s2, g4[col], bb4[col], sc, sh);
        scP[tid] = sc;
        shP[tid] = b4[col] * sc + sh;   // bias folded
        hwP[tid] = hw4[col];
    }
    __syncthreads();

    // ---- phase 1: s4 MFMA (identical order to stats pass)
    float4v acc[2][4][2];
    #pragma unroll
    for (int a = 0; a < 2; a++)
        #pragma unroll
        for (int b = 0; b < 4; b++)
            #pragma unroll
            for (int c = 0; c < 2; c++)
                acc[a][b][c] = (float4v){0.f, 0.f, 0.f, 0.f};

    #pragma unroll
    for (int ti = 0; ti < 2; ti++) {
        const int lt = w * 2 + ti;
        const int t = t0 + lt;
        short8 bf[2];
        #pragma unroll
        for (int nf = 0; nf < 2; nf++)
            bf[nf] = *(const short8*)(wbt4 + ((size_t)t * 20 + nf * 16 + l15) * 32 + quad * 8);
        #pragma unroll
        for (int mf = 0; mf < 4; mf++) {
            short8 a = *(const short8*)&gs[mf * 16 + l15][lt * 16 + quad * 8];
            #pragma unroll
            for (int nf = 0; nf < 2; nf++)
                acc[ti][mf][nf] = __builtin_amdgcn_mfma_f32_16x16x32_bf16(a, bf[nf], acc[ti][mf][nf], 0, 0, 0);
        }
    }

    // ---- phase 2: BN+tanh -> act into as_ + s4 head -> out
    #pragma unroll
    for (int ti = 0; ti < 2; ti++) {
        const int lt = w * 2 + ti;
        const int t4 = t0 + lt;
        float hp[4][4];
        #pragma unroll
        for (int mf = 0; mf < 4; mf++)
            #pragma unroll
            for (int r = 0; r < 4; r++) hp[mf][r] = 0.f;
        #pragma unroll
        for (int nf = 0; nf < 2; nf++) {
            const int o = nf * 16 + l15;
            const bool valid = (o < 20);
            const int lc = valid ? (lt * 20 + o) : 0;
            const float scale = valid ? scP[lc] : 0.f;
            const float shp   = valid ? shP[lc] : 0.f;
            const float hwv   = valid ? hwP[lc] : 0.f;
            #pragma unroll
            for (int mf = 0; mf < 4; mf++)
                #pragma unroll
                for (int r = 0; r < 4; r++) {
                    float av = fast_tanh(acc[ti][mf][nf][r] * scale + shp);
                    if (valid)
                        as_[mf * 16 + quad * 4 + r][lt * 20 + o] = f2bf(av);
                    hp[mf][r] += av * hwv;
                }
        }
        const float hbv = hb4[t4];
        #pragma unroll
        for (int mf = 0; mf < 4; mf++)
            #pragma unroll
            for (int r = 0; r < 4; r++) {
                float v = hp[mf][r];
                v += __shfl_xor(v, 1, 64); v += __shfl_xor(v, 2, 64);
                v += __shfl_xor(v, 4, 64); v += __shfl_xor(v, 8, 64);
                if (l15 == 0)
                    out[(size_t)(b0 + mf * 16 + quad * 4 + r) * OUTW + t4] = v + hbv;
            }
    }
    __syncthreads();   // as_ fully written before s3 reads

    // ---- phase 3: s3 MFMA
    const int t3l = w & 1, mh = w >> 1;
    const int t3 = cg * 2 + t3l;
    float4v acc3r[2][2];
    #pragma unroll
    for (int a = 0; a < 2; a++)
        #pragma unroll
        for (int b = 0; b < 2; b++)
            acc3r[a][b] = (float4v){0.f, 0.f, 0.f, 0.f};

    #pragma unroll
    for (int ks = 0; ks < 5; ks++) {
        const int k = ks * 32 + quad * 8;
        short8 bf[2];
        #pragma unroll
        for (int nf = 0; nf < 2; nf++)
            bf[nf] = *(const short8*)(wbt3 + ((size_t)t3 * 20 + nf * 16 + l15) * 192 + ks * 32 + quad * 8);
        #pragma unroll
        for (int mf2 = 0; mf2 < 2; mf2++) {
            const int row = (mh * 2 + mf2) * 16 + l15;
            const unsigned short* ap = (k < 80) ? &as_[row][t3l * 80 + k]
                                                : &gs[row][t3l * 64 + (k - 80)];
            short8 a = *(const short8*)ap;
            #pragma unroll
            for (int nf = 0; nf < 2; nf++)
                acc3r[mf2][nf] = __builtin_amdgcn_mfma_f32_16x16x32_bf16(a, bf[nf], acc3r[mf2][nf], 0, 0, 0);
        }
    }

    // ---- phase 4: h3 + atomic column stats -> acc3
    float ss_[2], ss2_[2];
    #pragma unroll
    for (int nf = 0; nf < 2; nf++) { ss_[nf] = 0.f; ss2_[nf] = 0.f; }
    #pragma unroll
    for (int mf2 = 0; mf2 < 2; mf2++)
        #pragma unroll
        for (int nf = 0; nf < 2; nf++) {
            const int o = nf * 16 + l15;
            const int col = t3 * 20 + o;
            const bool valid = (o < 20);
            const float bias = valid ? b3[col] : 0.f;
            #pragma unroll
            for (int r = 0; r < 4; r++) {
                const int m = (mh * 2 + mf2) * 16 + quad * 4 + r;
                float v = acc3r[mf2][nf][r] + bias;
                if (valid)
                    h3[(size_t)(b0 + m) * 1280 + col] = f2bf(v);
                ss_[nf] += v; ss2_[nf] += v * v;
            }
        }
    #pragma unroll
    for (int nf = 0; nf < 2; nf++) {
        ss_[nf]  += __shfl_xor(ss_[nf], 16, 64);  ss_[nf]  += __shfl_xor(ss_[nf], 32, 64);
        ss2_[nf] += __shfl_xor(ss2_[nf], 16, 64); ss2_[nf] += __shfl_xor(ss2_[nf], 32, 64);
        const int o = nf * 16 + l15;
        if (quad == 0 && o < 20) {
            const int col = t3 * 20 + o;
            atomicAdd(acc3 + col, ss_[nf]);
            atomicAdd(acc3 + 1280 + col, ss2_[nf]);
        }
    }
}

// ---- s2 GEMM + on-the-fly act3 (BN+tanh from acc3) + s3 head + s2 stats ----
__global__ __launch_bounds__(256) void s2_fused(
    const unsigned short* __restrict__ h3,    // [2048][1280] bf16 (raw pre-BN)
    const unsigned short* __restrict__ xg,    // bf16 x copy, row stride 5376
    const unsigned short* __restrict__ WbT,   // s2 region: [16][77][384]
    const float* __restrict__ acc3,           // [2][1280] s3 stats (complete)
    const float* __restrict__ g3, const float* __restrict__ bb3,
    const float* __restrict__ hw3, const float* __restrict__ hb3,
    const float* __restrict__ b2,
    unsigned short* __restrict__ h,           // [2048][1232]
    float* __restrict__ acc2,                 // [2][1232] atomic accumulators
    float* __restrict__ out)
{
    constexpr int BN = 96, BK = 64;
    constexpr int I = 336, O = 77, C = 80, Gs = 256, Kpad = 384;
    constexpr int hstride = 1232, TO = 1232;
    const int t  = blockIdx.z;
    const int b0 = blockIdx.y * 64;
    const int tid = threadIdx.x;
    const int lane = tid & 63;
    const int w = tid >> 6;
    const int l15 = lane & 15;
    const int quad = lane >> 4;

    constexpr int NF = BN / 32;               // 3
    const int wm = (w & 1) * 32;
    const int wn = (w >> 1) * (BN / 2);       // 0 / 48

    __shared__ __align__(16) unsigned short As[64][BK + 8];
    __shared__ __align__(16) unsigned short Bs[BN][BK + 8];
    __shared__ float ldsS[2][BN], ldsS2[2][BN];
    __shared__ float scL[80], shL[80], hwL[80];
    __shared__ float headAcc[64][4];

    if (tid < 80) {
        int col = t * 80 + tid;
        float sc, sh;
        bn_ss(acc3[col], acc3[1280 + col], g3[col], bb3[col], sc, sh);
        scL[tid] = sc; shL[tid] = sh; hwL[tid] = hw3[col];
    }
    headAcc[tid >> 2][tid & 3] = 0.f;
    __syncthreads();

    float4v accr[2][NF];
    #pragma unroll
    for (int a = 0; a < 2; a++)
        #pragma unroll
        for (int b = 0; b < NF; b++)
            accr[a][b] = (float4v){0.f, 0.f, 0.f, 0.f};

    constexpr int GR = BK / 8;     // 8
    constexpr int AG = 64 * GR;    // 512
    constexpr int BG = BN * GR;    // 768

    for (int k0 = 0; k0 < Kpad; k0 += BK) {
        #pragma unroll
        for (int g = tid; g < AG; g += 256) {
            const int r = g / GR, c8 = g % GR;
            const int k = k0 + c8 * 8;
            const int b = b0 + r;
            if (k + 8 <= C) {
                union { unsigned short u[8]; uint4 v; } hi_, ho;
                hi_.v = *(const uint4*)(h3 + (size_t)b * 1280 + t * 80 + k);
                const int tA = k / 20, tB = (k + 7) / 20;
                float pA = 0.f, pB = 0.f;
                #pragma unroll
                for (int j = 0; j < 8; j++) {
                    const int kk = k + j;
                    float av = fast_tanh(bf2f(hi_.u[j]) * scL[kk] + shL[kk]);
                    ho.u[j] = f2bf(av);
                    float pr = av * hwL[kk];
                    if (kk / 20 == tA) pA += pr; else pB += pr;
                }
                atomicAdd(&headAcc[r][tA], pA);
                if (tB != tA) atomicAdd(&headAcc[r][tB], pB);
                *(uint4*)&As[r][c8 * 8] = ho.v;
            } else if (k >= I) {
                *(uint4*)&As[r][c8 * 8] = make_uint4(0u, 0u, 0u, 0u);
            } else {
                *(uint4*)&As[r][c8 * 8] =
                    *(const uint4*)(xg + (size_t)b * 5376 + t * Gs + (k - C));
            }
        }
        #pragma unroll
        for (int g = tid; g < BG; g += 256) {
            const int n = g / GR, c8 = g % GR;
            uint4 v = make_uint4(0u, 0u, 0u, 0u);
            if (n < O)
                v = *(const uint4*)(WbT + ((size_t)t * O + n) * Kpad + k0 + c8 * 8);
            *(uint4*)&Bs[n][c8 * 8] = v;
        }
        __syncthreads();
        #pragma unroll
        for (int ks = 0; ks < BK / 32; ks++) {
            const int koff = ks * 32 + quad * 8;
            short8 a0 = *(const short8*)&As[wm + l15][koff];
            short8 a1 = *(const short8*)&As[wm + 16 + l15][koff];
            #pragma unroll
            for (int fn = 0; fn < NF; fn++) {
                short8 bf = *(const short8*)&Bs[wn + fn * 16 + l15][koff];
                accr[0][fn] = __builtin_amdgcn_mfma_f32_16x16x32_bf16(a0, bf, accr[0][fn], 0, 0, 0);
                accr[1][fn] = __builtin_amdgcn_mfma_f32_16x16x32_bf16(a1, bf, accr[1][fn], 0, 0, 0);
            }
        }
        __syncthreads();
    }

    // s3 head out
    {
        const int r = tid >> 2, t3l = tid & 3;
        const int t3 = t * 4 + t3l;
        out[(size_t)(b0 + r) * OUTW + 256 + t3] = headAcc[r][t3l] + hb3[t3];
    }

    // epilogue + per-thread column partial sums (fp32, pre-rounding)
    float csum[NF], csum2[NF];
    #pragma unroll
    for (int fn = 0; fn < NF; fn++) { csum[fn] = 0.f; csum2[fn] = 0.f; }
    #pragma unroll
    for (int fm = 0; fm < 2; fm++)
        #pragma unroll
        for (int fn = 0; fn < NF; fn++)
            #pragma unroll
            for (int r = 0; r < 4; r++) {
                int m = wm + fm * 16 + quad * 4 + r;
                int o = wn + fn * 16 + l15;
                if (o < O) {
                    float v = accr[fm][fn][r] + b2[t * O + o];
                    h[(size_t)(b0 + m) * hstride + (size_t)t * O + o] = f2bf(v);
                    csum[fn] += v; csum2[fn] += v * v;
                }
            }
    #pragma unroll
    for (int fn = 0; fn < NF; fn++) {
        csum[fn]  += __shfl_xor(csum[fn], 16, 64);
        csum[fn]  += __shfl_xor(csum[fn], 32, 64);
        csum2[fn] += __shfl_xor(csum2[fn], 16, 64);
        csum2[fn] += __shfl_xor(csum2[fn], 32, 64);
    }
    if (quad == 0) {
        #pragma unroll
        for (int fn = 0; fn < NF; fn++) {
            ldsS[w & 1][wn + fn * 16 + l15]  = csum[fn];
            ldsS2[w & 1][wn + fn * 16 + l15] = csum2[fn];
        }
    }
    __syncthreads();
    if (tid < BN && tid < O) {
        int col = t * O + tid;
        atomicAdd(acc2 + col,      ldsS[0][tid] + ldsS[1][tid]);
        atomicAdd(acc2 + TO + col, ldsS2[0][tid] + ldsS2[1][tid]);
    }
}

// ---- big-stage GEMM (s1/s0): 128-row tile, BK=32, dbuf LDS, XCD-swizzled 1D grid
// (round-8 proven body, FROZEN -- r9/r10/r11/r16 all regressed).
template <int BN>
__global__ __launch_bounds__(256) void gemm_split(
    const unsigned short* __restrict__ A,     // [2048][aStride] bf16 (zero-padded)
    const unsigned short* __restrict__ WbT,   // [T][Npad][Kpad] bf16 (zero-padded)
    float* __restrict__ partial,              // [KS][2048][TNpad]
    int aStride, int tStride, int Kpad, int Npad, int KS, int TNpad,
    int nTiles, int TKS)
{
    const int tid = threadIdx.x;
    const int lane = tid & 63, w = tid >> 6;
    const int l15 = lane & 15, quad = lane >> 4;

    // swizzled decode
    const int id = blockIdx.x;
    const int c = id & 7;
    const int tmp = id >> 3;
    const int n = tmp % nTiles;
    const int q = tmp / nTiles;
    const int group = q * 8 + c;
    const int b0 = (group / TKS) * 128;
    const int rem = group % TKS;
    const int t = rem / KS;
    const int ksIdx = rem - t * KS;
    const int n0 = n * BN;

    __shared__ __align__(16) unsigned short As[2][128 * 32];   // 2 x 8 KB
    __shared__ __align__(16) unsigned short Bs[2][BN * 32];    // 2 x 8/4 KB

    const int S = Kpad >> 5;
    const int qb = S / KS, rb = S % KS;
    const int beg = ksIdx * qb + (ksIdx < rb ? ksIdx : rb);
    const int cnt = qb + (ksIdx < rb ? 1 : 0);

    constexpr int NF = BN / 32;
    const int wm = (w & 1) * 64;
    const int wn = (w >> 1) * (BN / 2);

    float4v acc[4][NF];
    #pragma unroll
    for (int a = 0; a < 4; a++)
        #pragma unroll
        for (int b = 0; b < NF; b++)
            acc[a][b] = (float4v){0.f, 0.f, 0.f, 0.f};

    // A staging: 512 granule-slots, 2 calls/wave
    const unsigned short* aSrc[2];
    int aOff[2];
    #pragma unroll
    for (int j = 0; j < 2; j++) {
        int s = (w * 2 + j) * 64 + lane;
        int r = s >> 2, kg = (s & 3) ^ ((r >> 1) & 3);
        aSrc[j] = A + (size_t)(b0 + r) * aStride + (size_t)t * tStride + kg * 8;
        aOff[j] = (w * 2 + j) * 512;           // shorts
    }
    // B staging
    constexpr int BCALLS = (BN == 128) ? 2 : 1;
    const unsigned short* bSrc[BCALLS];
    int bOff[BCALLS];
    #pragma unroll
    for (int j = 0; j < BCALLS; j++) {
        int s = (w * BCALLS + j) * 64 + lane;
        int r = s >> 2, kg = (s & 3) ^ ((r >> 1) & 3);
        bSrc[j] = WbT + ((size_t)t * Npad + n0 + r) * Kpad + kg * 8;
        bOff[j] = (w * BCALLS + j) * 512;
    }

    // prologue: stage step 0 into buf 0
    {
        const int k0 = beg << 5;
        #pragma unroll
        for (int j = 0; j < 2; j++)      stage16(aSrc[j] + k0, &As[0][aOff[j]], lane);
        #pragma unroll
        for (int j = 0; j < BCALLS; j++) stage16(bSrc[j] + k0, &Bs[0][bOff[j]], lane);
    }

    for (int s = 0; s < cnt; s++) {
        const int cur = s & 1;
        __syncthreads();   // drains cur-buf loads (in flight since prev iter) + prev compute
        if (s + 1 < cnt) {
            const int k1 = (beg + s + 1) << 5;
            #pragma unroll
            for (int j = 0; j < 2; j++)      stage16(aSrc[j] + k1, &As[cur ^ 1][aOff[j]], lane);
            #pragma unroll
            for (int j = 0; j < BCALLS; j++) stage16(bSrc[j] + k1, &Bs[cur ^ 1][bOff[j]], lane);
        }
        short8 af[4];
        #pragma unroll
        for (int fm = 0; fm < 4; fm++) {
            int m = wm + fm * 16 + l15;
            int pos = quad ^ ((m >> 1) & 3);
            af[fm] = *(const short8*)&As[cur][(m * 4 + pos) * 8];
        }
        short8 bfr[NF];
        #pragma unroll
        for (int fn = 0; fn < NF; fn++) {
            int nn = wn + fn * 16 + l15;
            int pos = quad ^ ((nn >> 1) & 3);
            bfr[fn] = *(const short8*)&Bs[cur][(nn * 4 + pos) * 8];
        }
        #pragma unroll
        for (int fm = 0; fm < 4; fm++)
            #pragma unroll
            for (int fn = 0; fn < NF; fn++)
                acc[fm][fn] = __builtin_amdgcn_mfma_f32_16x16x32_bf16(af[fm], bfr[fn], acc[fm][fn], 0, 0, 0);
    }

    const size_t pBase = ((size_t)ksIdx * BDIM + b0) * TNpad + (size_t)t * Npad + n0;
    #pragma unroll
    for (int fm = 0; fm < 4; fm++)
        #pragma unroll
        for (int r = 0; r < 4; r++) {
            const int m = wm + fm * 16 + quad * 4 + r;
            float* prow = partial + pBase + (size_t)m * TNpad + wn;
            #pragma unroll
            for (int fn = 0; fn < NF; fn++)
                prow[fn * 16 + l15] = acc[fm][fn][r];
        }
}

// ---- s1 split-K reduce + W0 rows [0,512) cvt, one launch (flat grid) ----
__global__ __launch_bounds__(256) void reduce1_cvtw0(
    const float* __restrict__ partial, const float* __restrict__ bias,
    unsigned short* __restrict__ h, float* __restrict__ acc,
    const float* __restrict__ W0, unsigned short* __restrict__ wbt)
{
    __shared__ __align__(16) unsigned short tile[32 * 72];
    const int bid = blockIdx.x;
    if (bid >= 320) {
        int local = bid - 320;
        int bx = local % 84, by = local / 84;   // by in [0,16)
        cvt_w64(W0, wbt, 5328, 1229, 1280, 5376, bx * 64, by * 32, threadIdx.x, tile);
        return;
    }
    constexpr int T = 4, O = 308, Npad = 320, KS = 2, hstride = 1232, TO = 1232;
    __shared__ float redS[4][64], redS2[4][64];
    const int colL = threadIdx.x & 63;
    const int cr = threadIdx.x >> 6;
    const int col = (bid % 20) * 64 + colL;
    const int chunk = bid / 20;
    float s = 0.f, s2 = 0.f;
    if (col < TO) {
        int t = col / O, o = col - t * O;
        const size_t TNpad = (size_t)T * Npad;
        const size_t pcol = (size_t)t * Npad + o;
        const float bv = bias[col];
        const int row0 = chunk * 128 + cr * 32;
        for (int r = 0; r < 32; r++) {
            const int row = row0 + r;
            const float* p = partial + (size_t)row * TNpad + pcol;
            float v = bv;
            for (int ks = 0; ks < KS; ks++) v += p[(size_t)ks * BDIM * TNpad];
            h[(size_t)row * hstride + col] = f2bf(v);
            s += v; s2 += v * v;
        }
    }
    redS[cr][colL] = s; redS2[cr][colL] = s2;
    __syncthreads();
    if (cr == 0 && col < TO) {
        float ts  = redS[0][colL] + redS[1][colL] + redS[2][colL] + redS[3][colL];
        float ts2 = redS2[0][colL] + redS2[1][colL] + redS2[2][colL] + redS2[3][colL];
        atomicAdd(acc + col, ts);
        atomicAdd(acc + TO + col, ts2);
    }
}

// ---- s0 split-K reduce, VECTORIZED (r19): grid dim3(5,128); thread = 4 cols
// (float4) x 4 rows; wave reads 1KB contiguous per (row,ks). h uint2 stores.
// Stats: LDS wave-reduce -> 1 atomicAdd pair per col per block.
// T=1 so col->pcol is identity; partial cols [1229,1280) are exact zeros
// (wbt rows zero-padded), bias guarded -> pad writes f2bf(0), never read.
__global__ __launch_bounds__(256) void reduce0_vec(
    const float* __restrict__ partial, const float* __restrict__ bias,
    unsigned short* __restrict__ h, float* __restrict__ acc)
{
    constexpr int Npad = 1280, KS = 4, hstride = 1232, O = 1229;
    const int tid = threadIdx.x;
    const int lane = tid & 63, wv = tid >> 6;
    const int c4 = blockIdx.x * 256 + lane * 4;
    const int row0 = blockIdx.y * 16 + wv * 4;
    __shared__ float redS[4][256], redS2[4][256];

    float4 bv = make_float4(0.f, 0.f, 0.f, 0.f);
    if (c4 + 4 <= O) {
        bv = *(const float4*)(bias + c4);
    } else {
        if (c4 + 0 < O) bv.x = bias[c4 + 0];
        if (c4 + 1 < O) bv.y = bias[c4 + 1];
        if (c4 + 2 < O) bv.z = bias[c4 + 2];
        if (c4 + 3 < O) bv.w = bias[c4 + 3];
    }

    float s0 = 0.f, s1 = 0.f, s2 = 0.f, s3 = 0.f;
    float q0 = 0.f, q1 = 0.f, q2 = 0.f, q3 = 0.f;
    #pragma unroll
    for (int r = 0; r < 4; r++) {
        const int row = row0 + r;
        const float* p = partial + (size_t)row * Npad + c4;
        float4 v = bv;
        #pragma unroll
        for (int ks = 0; ks < KS; ks++) {
            float4 pv = *(const float4*)(p + (size_t)ks * BDIM * Npad);
            v.x += pv.x; v.y += pv.y; v.z += pv.z; v.w += pv.w;
        }
        if (c4 + 4 <= hstride) {
            union { unsigned short u[4]; uint2 d; } o;
            o.u[0] = f2bf(v.x); o.u[1] = f2bf(v.y); o.u[2] = f2bf(v.z); o.u[3] = f2bf(v.w);
            *(uint2*)(h + (size_t)row * hstride + c4) = o.d;
        }
        s0 += v.x; s1 += v.y; s2 += v.z; s3 += v.w;
        q0 += v.x * v.x; q1 += v.y * v.y; q2 += v.z * v.z; q3 += v.w * v.w;
    }
    const int ci = lane * 4;
    redS[wv][ci + 0] = s0; redS[wv][ci + 1] = s1; redS[wv][ci + 2] = s2; redS[wv][ci + 3] = s3;
    redS2[wv][ci + 0] = q0; redS2[wv][ci + 1] = q1; redS2[wv][ci + 2] = q2; redS2[wv][ci + 3] = q3;
    __syncthreads();
    {
        const int col = blockIdx.x * 256 + tid;
        if (col < O) {
            float ts  = redS[0][tid] + redS[1][tid] + redS[2][tid] + redS[3][tid];
            float tq  = redS2[0][tid] + redS2[1][tid] + redS2[2][tid] + redS2[3][tid];
            atomicAdd(acc + col, ts);
            atomicAdd(acc + O + col, tq);
        }
    }
}

// ---- BN(from acc) + tanh + strided act store + head — WAVE variant ----
__global__ __launch_bounds__(256) void bn_tanh_head(
    const unsigned short* __restrict__ h, const float* __restrict__ acc,
    const float* __restrict__ g, const float* __restrict__ bb,
    const float* __restrict__ hw, const float* __restrict__ hb,
    unsigned short* __restrict__ actOut, float* __restrict__ out,
    int T, int O, int hstride, int aRow, int GT, int GS, int head_off, int TO)
{
    int wid  = (blockIdx.x * 256 + threadIdx.x) >> 6;
    int lane = threadIdx.x & 63;
    int b = wid / T;
    int t = wid % T;
    const size_t hbase = (size_t)b * hstride + (size_t)t * O;
    const size_t abase = (size_t)b * aRow + (size_t)(t / GT) * GS + (size_t)(t % GT) * O;
    float hsum = 0.f;
    for (int o = lane; o < O; o += 64) {
        int col = t * O + o;
        float sc, sh;
        bn_ss(acc[col], acc[TO + col], g[col], bb[col], sc, sh);
        float a = fast_tanh(bf2f(h[hbase + o]) * sc + sh);
        if (actOut) actOut[abase + o] = f2bf(a);
        hsum += a * hw[col];
    }
    #pragma unroll
    for (int off = 32; off > 0; off >>= 1) hsum += __shfl_down(hsum, off, 64);
    if (lane == 0) out[(size_t)b * OUTW + head_off + t] = hsum + hb[t];
}

extern "C" void kernel_launch(void* const* d_in, const int* in_sizes, int n_in,
                              void* d_out, int out_size, void* d_ws, size_t ws_size,
                              hipStream_t stream)
{
    const float* x = (const float*)d_in[0];
    float* out = (float*)d_out;
    char* ws = (char*)d_ws;

    // ws layout (bytes)
    unsigned short* wbt  = (unsigned short*)(ws);              // 13,762,560
    unsigned short* ain0 = (unsigned short*)(ws + 13762560);   // 22,020,096 (2048x5376)
    unsigned short* bufB = (unsigned short*)(ws + 56754176);   //  5,242,880
    unsigned short* ain1 = (unsigned short*)(ws + 61997056);   // 22,020,096
    unsigned short* bufC = (unsigned short*)(ws + 84017152);   //  5,046,272
    float*          accB = (float*)(ws + 89063424);            //  81 KB stat accumulators
    // overlays (all verified dead at use time):
    float* partial = (float*)(ws + 35782656);   // s1: 21 MB, s0: 41.9 MB (dead regions)
    unsigned short* xg = ain0 + 1232;           // full bf16 x copy, row stride 5376
    float* sp4 = (float*)bufC;                  // 32x2x5120x4 = 1.31 MB (bufC dead until s2_fused h2)
    // per-stage atomic stat accumulators (sum[TO] then sumsq[TO]):
    float* acc3 = accB + 10240;    // 2x1280
    float* acc2 = accB + 12800;    // 2x1232
    float* acc1 = accB + 15264;    // 2x1232
    float* acc0 = accB + 17728;    // 2x1229

    const float* W4 = (const float*)d_in[1];  const float* b4 = (const float*)d_in[2];
    const float* g4 = (const float*)d_in[3];  const float* bb4 = (const float*)d_in[4];
    const float* hw4 = (const float*)d_in[5]; const float* hb4 = (const float*)d_in[6];
    const float* W3 = (const float*)d_in[7];  const float* b3 = (const float*)d_in[8];
    const float* g3 = (const float*)d_in[9];  const float* bb3 = (const float*)d_in[10];
    const float* hw3 = (const float*)d_in[11]; const float* hb3 = (const float*)d_in[12];
    const float* W2 = (const float*)d_in[13]; const float* b2 = (const float*)d_in[14];
    const float* g2 = (const float*)d_in[15]; const float* bb2 = (const float*)d_in[16];
    const float* hw2 = (const float*)d_in[17]; const float* hb2 = (const float*)d_in[18];
    const float* W1 = (const float*)d_in[19]; const float* b1 = (const float*)d_in[20];
    const float* g1 = (const float*)d_in[21]; const float* bb1 = (const float*)d_in[22];
    const float* hw1 = (const float*)d_in[23]; const float* hb1 = (const float*)d_in[24];
    const float* W0 = (const float*)d_in[25]; const float* b0_ = (const float*)d_in[26];
    const float* g0 = (const float*)d_in[27]; const float* bb0 = (const float*)d_in[28];
    const float* hw0 = (const float*)d_in[29]; const float* hb0 = (const float*)d_in[30];

    // 1: fused x pack + W cvts (vectorized) + acc zeroing + s4 chunk stats
    pack_cvt<<<PACK_BLOCKS + CVT_BLOCKS + W0P1_BLOCKS + STATS_BLOCKS, 256, 0, stream>>>(
        x, ain0, ain1, W4, W3, W2, W1, W0, wbt, accB, (const float*)wbt, b4, sp4);

    // 2: s4 act recompute (fold sp4 -> BN) + s3 GEMM: h3 -> bufB, stats -> acc3
    s4s3_fused<<<1024, 256, 0, stream>>>(xg, wbt, wbt + 163840, b4, sp4, g4, bb4,
                                         hw4, hb4, b3, bufB, acc3, out);

    // 3: s2 GEMM with on-the-fly act3 + s3 head + s2 stats (h2 -> bufC)
    s2_fused<<<dim3(1, 32, 16), 256, 0, stream>>>(bufB, xg, wbt + 409600, acc3,
                                                  g3, bb3, hw3, hb3, b2,
                                                  bufC, acc2, out);
    // 4: s2 BN+tanh -> act2 (ain1) + s2 head
    bn_tanh_head<<<BDIM * 16 / 4, 256, 0, stream>>>(bufC, acc2, g2, bb2, hw2, hb2,
                                                    ain1, out, 16, 77, 1232, 5376, 4, 1344, 320, 1232);

    // 5: s1 GEMM (T=4 I=1332 O=308 Kpad=1344 Npad=320 KS=2, WbT @882688)
    gemm_split<64><<<640, 256, 0, stream>>>(ain1, wbt + 882688, partial,
                                            5376, 1344, 1344, 320, 2, 1280, 5, 8);
    // 6: s1 reduce + W0 rows [0,512) cvt (h1 -> bufC)
    reduce1_cvtw0<<<320 + 84 * 16, 256, 0, stream>>>(partial, b1, bufC, acc1, W0, wbt);
    // 7: s1 BN+tanh -> act1 (ain0) + s1 head
    bn_tanh_head<<<BDIM * 4 / 4, 256, 0, stream>>>(bufC, acc1, g1, bb1, hw1, hb1,
                                                   ain0, out, 4, 308, 1232, 5376, 4, 0, 336, 1232);

    // 8: s0 GEMM (T=1 I=5328 O=1229 Kpad=5376 Npad=1280 KS=4)
    gemm_split<128><<<640, 256, 0, stream>>>(ain0, wbt, partial,
                                             5376, 0, 5376, 1280, 4, 1280, 10, 4);
    // 9: s0 reduce, vectorized (h0 -> bufC)
    reduce0_vec<<<dim3(5, 128), 256, 0, stream>>>(partial, b0_, bufC, acc0);
    // 10: s0 BN+tanh+head
    bn_tanh_head<<<BDIM / 4, 256, 0, stream>>>(bufC, acc0, g0, bb0, hw0, hb0,
                                               nullptr, out, 1, 1229, 1232, 1232, 1, 0, 340, 1229);
}